// Round 3
// baseline (329.048 us; speedup 1.0000x reference)
//
#include <hip/hip_runtime.h>

#define NL 7
#define NA 32
#define PERL 528
#define NF 3696
#define RSTRIDE 40                 // halves per staged row (80 B, bank-spread)
#define LBLK (NA * RSTRIDE)        // 1280 halves per l-block
#define SQRT2 1.41421356237309515f

typedef __attribute__((ext_vector_type(8))) short bf16x8;
typedef __attribute__((ext_vector_type(4))) float f32x4;

__device__ __forceinline__ unsigned f2bf(float f) {
    union { float f; unsigned u; } c; c.f = f;
    return (c.u + 0x7fffu + ((c.u >> 16) & 1u)) >> 16;   // RNE to bf16
}

__global__ __launch_bounds__(256) void ps_kernel(
    const float* __restrict__ se0, const float* __restrict__ se1,
    const float* __restrict__ se2, const float* __restrict__ se3,
    const float* __restrict__ se4, const float* __restrict__ se5,
    const float* __restrict__ se6, float* __restrict__ out)
{
    __shared__ unsigned short Th[NL * LBLK];   // 17920 B
    __shared__ float s_wsum[4];
    __shared__ float s_inv;

    const int j   = blockIdx.x;
    const int tid = threadIdx.x;

    const float* srcs[NL] = {se0, se1, se2, se3, se4, se5, se6};
    const float rs[NL] = {1.0f, 0.57735026919f, 0.44721359549f, 0.37796447301f,
                          0.33333333333f, 0.30151134457f, 0.27735009811f};

    // ---- phase 1: stage row a of l as bf16, zero-padded to K=32 ----
    if (tid < NL * NA) {
        const int l   = tid >> 5;
        const int a   = tid & 31;
        const int m21 = 2 * l + 1;
        const float* src = srcs[l] + (size_t)j * NA * m21 + (size_t)a * m21;
        unsigned short* row = Th + l * LBLK + a * RSTRIDE;
        #pragma unroll
        for (int mb = 0; mb < 32; mb += 8) {
            unsigned pk[4];
            #pragma unroll
            for (int p = 0; p < 4; ++p) {
                const int m0 = mb + 2 * p;
                const float g0 = (m0     < m21) ? src[m0]     : 0.0f;
                const float g1 = (m0 + 1 < m21) ? src[m0 + 1] : 0.0f;
                pk[p] = f2bf(g0) | (f2bf(g1) << 16);
            }
            *(uint4*)(row + mb) = make_uint4(pk[0], pk[1], pk[2], pk[3]);
        }
    }
    __syncthreads();

    // ---- phase 2: MFMA Gram tiles. wave w owns l = w and l = w+4 ----
    const int wv   = tid >> 6;
    const int lane = tid & 63;
    const int rowA  = lane & 15;          // A-frag row / C col
    const int koff  = (lane >> 4) << 3;   // k-block
    const int bcol  = lane & 15;
    const int abase = (lane >> 4) << 2;

    const f32x4 zz = {0.0f, 0.0f, 0.0f, 0.0f};
    f32x4 gA00 = zz, gA01 = zz, gA11 = zz;
    f32x4 gB00 = zz, gB01 = zz, gB11 = zz;
    const int lA = wv;
    const int lB = wv + 4;

    {
        const unsigned short* base = Th + lA * LBLK + koff;
        bf16x8 f0 = *(const bf16x8*)(base + rowA * RSTRIDE);
        bf16x8 f1 = *(const bf16x8*)(base + (rowA + 16) * RSTRIDE);
        gA00 = __builtin_amdgcn_mfma_f32_16x16x32_bf16(f0, f0, zz, 0, 0, 0);
        gA01 = __builtin_amdgcn_mfma_f32_16x16x32_bf16(f0, f1, zz, 0, 0, 0);
        gA11 = __builtin_amdgcn_mfma_f32_16x16x32_bf16(f1, f1, zz, 0, 0, 0);
    }
    if (lB < NL) {
        const unsigned short* base = Th + lB * LBLK + koff;
        bf16x8 f0 = *(const bf16x8*)(base + rowA * RSTRIDE);
        bf16x8 f1 = *(const bf16x8*)(base + (rowA + 16) * RSTRIDE);
        gB00 = __builtin_amdgcn_mfma_f32_16x16x32_bf16(f0, f0, zz, 0, 0, 0);
        gB01 = __builtin_amdgcn_mfma_f32_16x16x32_bf16(f0, f1, zz, 0, 0, 0);
        gB11 = __builtin_amdgcn_mfma_f32_16x16x32_bf16(f1, f1, zz, 0, 0, 0);
    }

    // ---- phase 3: ssq partials straight from accumulators ----
    float ssq = 0.0f;
    auto acc_tile = [&](const f32x4& g, int r0, int c0, float rsl) {
        #pragma unroll
        for (int r = 0; r < 4; ++r) {
            const int a = r0 + abase + r;
            const int b = c0 + bcol;
            const float v = g[r] * rsl;
            if (a == b)      ssq += v * v;
            else if (a < b)  ssq += 2.0f * v * v;
        }
    };
    acc_tile(gA00, 0,  0,  rs[lA]);
    acc_tile(gA01, 0,  16, rs[lA]);
    acc_tile(gA11, 16, 16, rs[lA]);
    if (lB < NL) {
        acc_tile(gB00, 0,  0,  rs[lB]);
        acc_tile(gB01, 0,  16, rs[lB]);
        acc_tile(gB11, 16, 16, rs[lB]);
    }

    #pragma unroll
    for (int off = 32; off >= 1; off >>= 1) ssq += __shfl_down(ssq, off, 64);
    if (lane == 0) s_wsum[wv] = ssq;
    __syncthreads();
    if (tid == 0) {
        const float tot = s_wsum[0] + s_wsum[1] + s_wsum[2] + s_wsum[3];
        s_inv = 1.0f / fmaxf(sqrtf(tot), 1e-12f);
    }
    __syncthreads();
    const float inv = s_inv;

    // ---- phase 4: normalized scattered stores from registers ----
    float* op = out + (size_t)j * NF;
    auto st_tile = [&](const f32x4& g, int r0, int c0, int l) {
        float* ol = op + l * PERL;
        const float dsc = rs[l] * inv;
        const float usc = SQRT2 * dsc;
        #pragma unroll
        for (int r = 0; r < 4; ++r) {
            const int a = r0 + abase + r;
            const int b = c0 + bcol;
            const float v = g[r];
            if (a == b)      ol[a] = v * dsc;
            else if (a < b)  ol[32 + a * (63 - a) / 2 + (b - a - 1)] = v * usc;
        }
    };
    st_tile(gA00, 0,  0,  lA);
    st_tile(gA01, 0,  16, lA);
    st_tile(gA11, 16, 16, lA);
    if (lB < NL) {
        st_tile(gB00, 0,  0,  lB);
        st_tile(gB01, 0,  16, lB);
        st_tile(gB11, 16, 16, lB);
    }
}

extern "C" void kernel_launch(void* const* d_in, const int* in_sizes, int n_in,
                              void* d_out, int out_size, void* d_ws, size_t ws_size,
                              hipStream_t stream) {
    const float* se0 = (const float*)d_in[0];
    const float* se1 = (const float*)d_in[1];
    const float* se2 = (const float*)d_in[2];
    const float* se3 = (const float*)d_in[3];
    const float* se4 = (const float*)d_in[4];
    const float* se5 = (const float*)d_in[5];
    const float* se6 = (const float*)d_in[6];
    float* out = (float*)d_out;

    const int J = in_sizes[0] / NA;   // se_0 is (J, 32, 1)
    ps_kernel<<<J, 256, 0, stream>>>(se0, se1, se2, se3, se4, se5, se6, out);
}

// Round 4
// 204.823 us; speedup vs baseline: 1.6065x; 1.6065x over previous
//
#include <hip/hip_runtime.h>

#define NL 7
#define NA 32
#define PERL 528
#define NF 3696
#define RSTRIDE 40                 // halves per staged row (80 B)
#define LBLK (NA * RSTRIDE)        // 1280 halves per l-block
#define SQRT2 1.41421356237309515f

typedef __attribute__((ext_vector_type(8))) short bf16x8;
typedef __attribute__((ext_vector_type(4))) float f32x4;

__device__ __forceinline__ unsigned f2bf(float f) {
    union { float f; unsigned u; } c; c.f = f;
    return (c.u + 0x7fffu + ((c.u >> 16) & 1u)) >> 16;   // RNE to bf16
}

__global__ __launch_bounds__(256) void ps_kernel(
    const float* __restrict__ se0, const float* __restrict__ se1,
    const float* __restrict__ se2, const float* __restrict__ se3,
    const float* __restrict__ se4, const float* __restrict__ se5,
    const float* __restrict__ se6, float* __restrict__ out)
{
    __shared__ __align__(16) unsigned short Th[NL * LBLK];   // 17920 B, reused as float Ob[3696]
    __shared__ float s_wsum[4];
    __shared__ float s_inv;
    float* Ob = (float*)Th;

    const int j   = blockIdx.x;
    const int tid = threadIdx.x;

    // ---- phase 0: zero LDS (covers k-padding) ----
    {
        uint4* z = (uint4*)Th;
        #pragma unroll
        for (int i = tid; i < 1120; i += 256) z[i] = make_uint4(0u, 0u, 0u, 0u);
    }
    __syncthreads();

    // ---- phase 1: coalesced float4 staging -> bf16 scatter into padded rows ----
    for (int g = tid; g < 392; g += 256) {
        const int e0 = 4 * g;
        int l, eL, a, m, m21;
        const float* srcp;
        if (e0 < 32)        { l = 0; m21 = 1;  eL = e0;        a = eL;      m = 0;            srcp = se0 + (size_t)j * 32  + eL; }
        else if (e0 < 128)  { l = 1; m21 = 3;  eL = e0 - 32;   a = eL / 3;  m = eL - a * 3;   srcp = se1 + (size_t)j * 96  + eL; }
        else if (e0 < 288)  { l = 2; m21 = 5;  eL = e0 - 128;  a = eL / 5;  m = eL - a * 5;   srcp = se2 + (size_t)j * 160 + eL; }
        else if (e0 < 512)  { l = 3; m21 = 7;  eL = e0 - 288;  a = eL / 7;  m = eL - a * 7;   srcp = se3 + (size_t)j * 224 + eL; }
        else if (e0 < 800)  { l = 4; m21 = 9;  eL = e0 - 512;  a = eL / 9;  m = eL - a * 9;   srcp = se4 + (size_t)j * 288 + eL; }
        else if (e0 < 1152) { l = 5; m21 = 11; eL = e0 - 800;  a = eL / 11; m = eL - a * 11;  srcp = se5 + (size_t)j * 352 + eL; }
        else                { l = 6; m21 = 13; eL = e0 - 1152; a = eL / 13; m = eL - a * 13;  srcp = se6 + (size_t)j * 416 + eL; }
        const float4 v = *(const float4*)srcp;
        unsigned short* base = Th + l * LBLK;
        const float vv[4] = {v.x, v.y, v.z, v.w};
        int aa = a, mm = m;
        #pragma unroll
        for (int i = 0; i < 4; ++i) {
            base[aa * RSTRIDE + mm] = (unsigned short)f2bf(vv[i]);
            if (++mm == m21) { mm = 0; ++aa; }
        }
    }
    __syncthreads();

    // ---- phase 2: MFMA Gram tiles. wave w owns l = w and l = w+4 ----
    const int wv    = tid >> 6;
    const int lane  = tid & 63;
    const int rowA  = lane & 15;          // A-frag row / C col
    const int koff  = (lane >> 4) << 3;   // k-block
    const int bcol  = lane & 15;
    const int abase = (lane >> 4) << 2;

    const f32x4 zz = {0.0f, 0.0f, 0.0f, 0.0f};
    f32x4 gA00 = zz, gA01 = zz, gA11 = zz;
    f32x4 gB00 = zz, gB01 = zz, gB11 = zz;
    const int lA = wv;
    const int lB = wv + 4;
    const float rsA = rsqrtf((float)(2 * lA + 1));
    const float rsB = rsqrtf((float)(2 * lB + 1));

    {
        const unsigned short* base = Th + lA * LBLK + koff;
        bf16x8 f0 = *(const bf16x8*)(base + rowA * RSTRIDE);
        bf16x8 f1 = *(const bf16x8*)(base + (rowA + 16) * RSTRIDE);
        gA00 = __builtin_amdgcn_mfma_f32_16x16x32_bf16(f0, f0, zz, 0, 0, 0);
        gA01 = __builtin_amdgcn_mfma_f32_16x16x32_bf16(f0, f1, zz, 0, 0, 0);
        gA11 = __builtin_amdgcn_mfma_f32_16x16x32_bf16(f1, f1, zz, 0, 0, 0);
    }
    if (lB < NL) {
        const unsigned short* base = Th + lB * LBLK + koff;
        bf16x8 f0 = *(const bf16x8*)(base + rowA * RSTRIDE);
        bf16x8 f1 = *(const bf16x8*)(base + (rowA + 16) * RSTRIDE);
        gB00 = __builtin_amdgcn_mfma_f32_16x16x32_bf16(f0, f0, zz, 0, 0, 0);
        gB01 = __builtin_amdgcn_mfma_f32_16x16x32_bf16(f0, f1, zz, 0, 0, 0);
        gB11 = __builtin_amdgcn_mfma_f32_16x16x32_bf16(f1, f1, zz, 0, 0, 0);
    }

    // ---- phase 3: branch-free Frobenius ssq ----
    float ssq = 0.0f;
    {
        float sA = 0.0f, sB = 0.0f;
        #pragma unroll
        for (int r = 0; r < 4; ++r) {
            sA += gA00[r] * gA00[r] + 2.0f * gA01[r] * gA01[r] + gA11[r] * gA11[r];
            sB += gB00[r] * gB00[r] + 2.0f * gB01[r] * gB01[r] + gB11[r] * gB11[r];
        }
        ssq = rsA * rsA * sA + ((lB < NL) ? rsB * rsB * sB : 0.0f);
    }

    #pragma unroll
    for (int off = 32; off >= 1; off >>= 1) ssq += __shfl_down(ssq, off, 64);
    if (lane == 0) s_wsum[wv] = ssq;
    __syncthreads();
    if (tid == 0) {
        const float tot = s_wsum[0] + s_wsum[1] + s_wsum[2] + s_wsum[3];
        s_inv = 1.0f / fmaxf(sqrtf(tot), 1e-12f);
    }
    __syncthreads();
    const float inv = s_inv;

    // ---- phase 4: scatter normalized values into LDS out buffer ----
    auto sc_tile = [&](const f32x4& g, int r0, int c0, int l, float rsl) {
        float* ol = Ob + l * PERL;
        const float dsc = rsl * inv;
        const float usc = SQRT2 * dsc;
        #pragma unroll
        for (int r = 0; r < 4; ++r) {
            const int a = r0 + abase + r;
            const int b = c0 + bcol;
            const float v = g[r];
            if (a == b)      ol[a] = v * dsc;
            else if (a < b)  ol[32 + a * (63 - a) / 2 + (b - a - 1)] = v * usc;
        }
    };
    sc_tile(gA00, 0,  0,  lA, rsA);
    sc_tile(gA01, 0,  16, lA, rsA);
    sc_tile(gA11, 16, 16, lA, rsA);
    if (lB < NL) {
        sc_tile(gB00, 0,  0,  lB, rsB);
        sc_tile(gB01, 0,  16, lB, rsB);
        sc_tile(gB11, 16, 16, lB, rsB);
    }
    __syncthreads();

    // ---- phase 5: coalesced float4 output ----
    {
        const float4* ob4 = (const float4*)Ob;
        float4* op4 = (float4*)(out + (size_t)j * NF);
        #pragma unroll
        for (int q = tid; q < 924; q += 256) op4[q] = ob4[q];
    }
}

extern "C" void kernel_launch(void* const* d_in, const int* in_sizes, int n_in,
                              void* d_out, int out_size, void* d_ws, size_t ws_size,
                              hipStream_t stream) {
    const float* se0 = (const float*)d_in[0];
    const float* se1 = (const float*)d_in[1];
    const float* se2 = (const float*)d_in[2];
    const float* se3 = (const float*)d_in[3];
    const float* se4 = (const float*)d_in[4];
    const float* se5 = (const float*)d_in[5];
    const float* se6 = (const float*)d_in[6];
    float* out = (float*)d_out;

    const int J = in_sizes[0] / NA;   // se_0 is (J, 32, 1)
    ps_kernel<<<J, 256, 0, stream>>>(se0, se1, se2, se3, se4, se5, se6, out);
}